// Round 7
// baseline (260.736 us; speedup 1.0000x reference)
//
#include <hip/hip_runtime.h>
#include <math.h>

#define NIMG 32
#define NB3  771             // 257 rings * 3 sums
#define PI_F 3.14159265358979323846f

// ---------------------------------------------------------------------------
__device__ __forceinline__ float2 cadd(float2 a, float2 b){ return make_float2(a.x+b.x, a.y+b.y); }
__device__ __forceinline__ float2 csub(float2 a, float2 b){ return make_float2(a.x-b.x, a.y-b.y); }
__device__ __forceinline__ float2 cmul(float2 a, float2 b){ return make_float2(a.x*b.x - a.y*b.y, a.x*b.y + a.y*b.x); }
__device__ __forceinline__ float2 cmul_mi(float2 a){ return make_float2(a.y, -a.x); }   // * (-i)
__device__ __forceinline__ float2 tw(const float2* T, int m){ return T[m + (m >> 3)]; }

// 8-point DFT (DIF, natural-order outputs), e^{-2pi i/8} convention
__device__ __forceinline__ void dft8(float2* x) {
    const float c = 0.70710678118654752f;
    float2 u0 = cadd(x[0], x[4]), u1 = cadd(x[1], x[5]);
    float2 u2 = cadd(x[2], x[6]), u3 = cadd(x[3], x[7]);
    float2 v0 = csub(x[0], x[4]);
    float2 d1 = csub(x[1], x[5]);
    float2 v1 = make_float2(c*(d1.x + d1.y), c*(d1.y - d1.x));
    float2 d2 = csub(x[2], x[6]);
    float2 v2 = make_float2(d2.y, -d2.x);
    float2 d3 = csub(x[3], x[7]);
    float2 v3 = make_float2(-c*(d3.x - d3.y), -c*(d3.x + d3.y));
    float2 e0 = cadd(u0,u2), e1 = cadd(u1,u3);
    float2 f0 = csub(u0,u2), f1 = cmul_mi(csub(u1,u3));
    float2 g0 = cadd(v0,v2), g1 = cadd(v1,v3);
    float2 h0 = csub(v0,v2), h1 = cmul_mi(csub(v1,v3));
    x[0] = cadd(e0,e1); x[4] = csub(e0,e1);
    x[2] = cadd(f0,f1); x[6] = csub(f0,f1);
    x[1] = cadd(g0,g1); x[5] = csub(g0,g1);
    x[3] = cadd(h0,h1); x[7] = csub(h0,h1);
}

// ---------------------------------------------------------------------------
// Per-wave 512-pt radix-8 DIF FFT, barrier-free (wave-private 576-slot LDS
// scratch). Thread J enters with X[q] = x[J + 64q], exits with
// X[k] = F(64k + r), r = 8*(J&7) + (J>>3).
// ---------------------------------------------------------------------------
__device__ __forceinline__ void wave_fft512(float2* X, float2* Sw,
                                            const float2* T, int J) {
    dft8(X);
#pragma unroll
    for (int k = 1; k < 8; ++k) X[k] = cmul(X[k], tw(T, J * k));
    const int jj = J + (J >> 3);
#pragma unroll
    for (int k = 0; k < 8; ++k) Sw[jj + 72*k] = X[k];

    const int j2 = J & 7;
    const int bb = 72 * (J >> 3) + j2;
#pragma unroll
    for (int q = 0; q < 8; ++q) X[q] = Sw[bb + 9*q];
    dft8(X);
#pragma unroll
    for (int k = 1; k < 8; ++k) X[k] = cmul(X[k], tw(T, 8 * j2 * k));
#pragma unroll
    for (int k = 0; k < 8; ++k) Sw[bb + 9*k] = X[k];

#pragma unroll
    for (int q = 0; q < 8; ++q) X[q] = Sw[9*J + q];
    dft8(X);
}

// ---------------------------------------------------------------------------
// Row pass (unchanged from R6 — control variable). Writes Zt[kx][y].
// ---------------------------------------------------------------------------
__global__ __launch_bounds__(256, 6) void fft_rows_T(const float* __restrict__ xr,
                                                     const float* __restrict__ yr,
                                                     float2* __restrict__ Zt) {
    __shared__ float2 S[4 * 576];
    __shared__ float2 T[576];
    const int t = threadIdx.x, w = t >> 6, J = t & 63;
    const int im = blockIdx.x >> 6, grp = blockIdx.x & 63;

#pragma unroll
    for (int i = 0; i < 2; ++i) {
        const int m = t + 256 * i;
        float sw, cw;
        __sincosf(-2.0f * PI_F * (float)m / 512.0f, &sw, &cw);
        T[m + (m >> 3)] = make_float2(cw, sw);
    }

    const size_t b0 = ((size_t)(im * 512 + grp * 8 + w)) << 9;
    const size_t b1 = b0 + (4u << 9);
    float2 X0[8], X1[8];
#pragma unroll
    for (int q = 0; q < 8; ++q) {
        X0[q] = make_float2(xr[b0 + J + 64*q], yr[b0 + J + 64*q]);
        X1[q] = make_float2(xr[b1 + J + 64*q], yr[b1 + J + 64*q]);
    }
    __syncthreads();                       // T ready

    float2* Sw = S + w * 576;
    wave_fft512(X0, Sw, T, J);
    wave_fft512(X1, Sw, T, J);

    const int r = ((J & 7) << 3) | (J >> 3);

#pragma unroll
    for (int k = 0; k < 8; ++k) Sw[64*k + r] = X0[k];
    __syncthreads();
    float2 eA[4], eB[4];
#pragma unroll
    for (int j = 0; j < 4; ++j) { eA[j] = S[j*576 + t]; eB[j] = S[j*576 + t + 256]; }
    __syncthreads();

#pragma unroll
    for (int k = 0; k < 8; ++k) Sw[64*k + r] = X1[k];
    __syncthreads();

    const size_t zb = ((size_t)im << 18) + (grp << 3);
    {
        float4* o = (float4*)(Zt + zb + ((size_t)t << 9));
        float2 f0 = S[0*576 + t], f1 = S[1*576 + t];
        float2 f2 = S[2*576 + t], f3 = S[3*576 + t];
        o[0] = make_float4(eA[0].x, eA[0].y, eA[1].x, eA[1].y);
        o[1] = make_float4(eA[2].x, eA[2].y, eA[3].x, eA[3].y);
        o[2] = make_float4(f0.x, f0.y, f1.x, f1.y);
        o[3] = make_float4(f2.x, f2.y, f3.x, f3.y);
    }
    {
        float4* o = (float4*)(Zt + zb + ((size_t)(t + 256) << 9));
        float2 f0 = S[0*576 + t + 256], f1 = S[1*576 + t + 256];
        float2 f2 = S[2*576 + t + 256], f3 = S[3*576 + t + 256];
        o[0] = make_float4(eB[0].x, eB[0].y, eB[1].x, eB[1].y);
        o[1] = make_float4(eB[2].x, eB[2].y, eB[3].x, eB[3].y);
        o[2] = make_float4(f0.x, f0.y, f1.x, f1.y);
        o[3] = make_float4(f2.x, f2.y, f3.x, f3.y);
    }
}

// ---------------------------------------------------------------------------
// Column FFT, IN-PLACE on Zt rows (each Zt row = one image column). Wave w
// does rows 8g+w and 8g+w+4. After FFT (digit-reversed in regs), park into
// wave-private scratch with swizzle addr = 64k + r + 2*(r>>3), then read
// natural order as float4 (addr 4J + (J&7) + i) and store coalesced.
// No ring math here — pure FFT probe kernel.
// ---------------------------------------------------------------------------
__global__ __launch_bounds__(256, 6) void fft_cols(float2* __restrict__ Zt) {
    __shared__ float2 S[4 * 576];
    __shared__ float2 T[576];
    const int t = threadIdx.x, w = t >> 6, J = t & 63;
    const int im = blockIdx.x >> 6, g = blockIdx.x & 63;

#pragma unroll
    for (int i = 0; i < 2; ++i) {
        const int m = t + 256 * i;
        float sw, cw;
        __sincosf(-2.0f * PI_F * (float)m / 512.0f, &sw, &cw);
        T[m + (m >> 3)] = make_float2(cw, sw);
    }

    const int c0 = 8 * g + w;
    const int c1 = c0 + 4;
    float2* rp0 = Zt + ((size_t)im << 18) + ((size_t)c0 << 9);
    float2* rp1 = Zt + ((size_t)im << 18) + ((size_t)c1 << 9);
    float2 X0[8], X1[8];
#pragma unroll
    for (int q = 0; q < 8; ++q) { X0[q] = rp0[J + 64*q]; X1[q] = rp1[J + 64*q]; }
    __syncthreads();                       // T ready

    float2* Sw = S + w * 576;
    const int r = ((J & 7) << 3) | (J >> 3);
    const int pk = r + 2 * (r >> 3);       // park swizzle offset

    wave_fft512(X0, Sw, T, J);
#pragma unroll
    for (int k = 0; k < 8; ++k) Sw[64*k + pk] = X0[k];
    {
        const float4* s4 = (const float4*)Sw;
        float4* d4 = (float4*)rp0;
#pragma unroll
        for (int i = 0; i < 4; ++i) d4[4*J + i] = s4[4*J + (J & 7) + i];
    }

    wave_fft512(X1, Sw, T, J);
#pragma unroll
    for (int k = 0; k < 8; ++k) Sw[64*k + pk] = X1[k];
    {
        const float4* s4 = (const float4*)Sw;
        float4* d4 = (float4*)rp1;
#pragma unroll
        for (int i = 0; i < 4; ++i) d4[4*J + i] = s4[4*J + (J & 7) + i];
    }
}

// ---------------------------------------------------------------------------
// Ring reduction probe kernel: no FFT, no twiddles. Wave w of block g owns
// mirror row pair p = 4g + w of the finished spectrum Zt[kx][ky]:
//   p = 0 : rows (0, 256), each self-mirror
//   p >= 1: rows (p, 512-p), same |fx| -> same ring
// Conjugate partner Z(-kx,-ky): other row, reversed ky -> register shuffle:
// ky = J + 64q  ->  partner lane (64-J)&63, reg 7-q (lane 0: own reg (8-q)&7).
// ---------------------------------------------------------------------------
__global__ __launch_bounds__(256) void rings(const float2* __restrict__ Zt,
                                             float* __restrict__ sums, int big) {
    __shared__ float bins[258 * 3];
    const int t = threadIdx.x, w = t >> 6, J = t & 63;
    const int im = blockIdx.x >> 6, g = blockIdx.x & 63;
    const int p = 4 * g + w;

    for (int i = t; i < 258 * 3; i += 256) bins[i] = 0.0f;

    const int c0 = (p == 0) ? 0   : p;
    const int c1 = (p == 0) ? 256 : 512 - p;
    const float2* rp0 = Zt + ((size_t)im << 18) + ((size_t)c0 << 9);
    const float2* rp1 = Zt + ((size_t)im << 18) + ((size_t)c1 << 9);
    float2 X0[8], X1[8];
#pragma unroll
    for (int q = 0; q < 8; ++q) { X0[q] = rp0[J + 64*q]; X1[q] = rp1[J + 64*q]; }
    __syncthreads();                       // bins zeroed

    const int Jp = (64 - J) & 63;
    const float scale = 1.0f / (512.0f * 512.0f);

    auto pix = [&](float2 zk, float2 zm, float& av, float& c1v, float& c2v) {
        float f1r = 0.5f * (zk.x + zm.x) * scale;
        float f1i = 0.5f * (zk.y - zm.y) * scale;
        float f2r = 0.5f * (zk.y + zm.y) * scale;
        float f2i = 0.5f * (zm.x - zk.x) * scale;
        av  = f1r * f2r + f1i * f2i;
        c1v = f1r * f1r + f1i * f1i;
        c2v = f2r * f2r + f2i * f2i;
    };
    auto dep = [&](int rr, float av, float c1v, float c2v) {
        if (rr > 256) rr = 257;
        unsafeAtomicAdd(&bins[rr*3+0], av);
        unsafeAtomicAdd(&bins[rr*3+1], c1v);
        unsafeAtomicAdd(&bins[rr*3+2], c2v);
    };

    const float fy2 = (float)p * (float)p;
#pragma unroll
    for (int q = 0; q < 8; ++q) {
        const int ky = J + 64 * q;
        const float fk = (ky < 256) ? (float)ky : (float)(ky - 512);
        const float fk2 = fk * fk;
        float2 zm0 = make_float2(__shfl(X0[7-q].x, Jp), __shfl(X0[7-q].y, Jp));
        float2 zm1 = make_float2(__shfl(X1[7-q].x, Jp), __shfl(X1[7-q].y, Jp));
        if (J == 0) { zm0 = X0[(8-q)&7]; zm1 = X1[(8-q)&7]; }
        if (p == 0) {
            float av, c1v, c2v;
            pix(X0[q], zm0, av, c1v, c2v);                 // row 0, fx=0
            dep((int)rintf(sqrtf(fk2)), av, c1v, c2v);
            pix(X1[q], zm1, av, c1v, c2v);                 // row 256, fx=256
            dep((int)rintf(sqrtf(fk2 + 65536.0f)), av, c1v, c2v);
        } else {
            float a1, b1, d1, a2, b2, d2;
            pix(X0[q], zm1, a1, b1, d1);   // (p, ky)     partner (512-p, -ky)
            pix(X1[q], zm0, a2, b2, d2);   // (512-p, ky) partner (p, -ky)
            dep((int)rintf(sqrtf(fk2 + fy2)), a1 + a2, b1 + b2, d1 + d2);
        }
    }
    __syncthreads();

    if (big) {
        float* dst = sums + (size_t)blockIdx.x * NB3;          // private slice
        for (int i = t; i < NB3; i += 256) dst[i] = bins[i];
    } else {
        float* dst = sums + (size_t)(im * 8 + (g & 7)) * NB3;  // shared slice
        for (int i = t; i < NB3; i += 256) unsafeAtomicAdd(&dst[i], bins[i]);
    }
}

// ---------------------------------------------------------------------------
// Finalize: block = image; sum spi slices per ring; mean of (1-frc)^2.
// C_i ring sums are exactly 0 by k -> -k antisymmetry; dropped.
// ---------------------------------------------------------------------------
__global__ __launch_bounds__(256) void finalize(const float* __restrict__ sums,
                                                float* __restrict__ out, int spi) {
    const int b = blockIdx.x, t = threadIdx.x;
    float acc = 0.0f;
    for (int r = t; r < 257; r += 256) {
        float cr = 0.f, c1 = 0.f, c2 = 0.f;
        for (int s = 0; s < spi; ++s) {
            const float* pp = sums + (size_t)(b * spi + s) * NB3 + r * 3;
            cr += pp[0]; c1 += pp[1]; c2 += pp[2];
        }
        float frc = fabsf(cr) / (sqrtf(c1 * c2) + 1e-8f);
        float d = 1.0f - frc;
        acc += d * d;
    }
#pragma unroll
    for (int off = 32; off > 0; off >>= 1) acc += __shfl_down(acc, off);
    __shared__ float red[4];
    if ((t & 63) == 0) red[t >> 6] = acc;
    __syncthreads();
    if (t == 0)
        unsafeAtomicAdd(out, (red[0] + red[1] + red[2] + red[3]) *
                             (1.0f / (257.0f * (float)NIMG)));
}

// ---------------------------------------------------------------------------
extern "C" void kernel_launch(void* const* d_in, const int* in_sizes, int n_in,
                              void* d_out, int out_size, void* d_ws, size_t ws_size,
                              hipStream_t stream) {
    const float* xr = (const float*)d_in[0];   // output: 32x1x512x512 f32
    const float* yr = (const float*)d_in[1];   // target: 32x1x512x512 f32

    float2* Zt = (float2*)d_ws;                                    // 64 MiB
    const size_t ztBytes = ((size_t)NIMG << 18) * sizeof(float2);
    float* sums = (float*)((char*)d_ws + ztBytes);
    const int big = (ws_size >= ztBytes + (size_t)2048 * NB3 * sizeof(float)) ? 1 : 0;

    if (!big)
        hipMemsetAsync(sums, 0, (size_t)NIMG * 8 * NB3 * sizeof(float), stream);
    hipMemsetAsync(d_out, 0, sizeof(float), stream);

    fft_rows_T<<<dim3(NIMG * 64), dim3(256), 0, stream>>>(xr, yr, Zt);
    fft_cols  <<<dim3(NIMG * 64), dim3(256), 0, stream>>>(Zt);
    rings     <<<dim3(NIMG * 64), dim3(256), 0, stream>>>(Zt, sums, big);
    finalize  <<<dim3(NIMG), dim3(256), 0, stream>>>(sums, (float*)d_out, big ? 64 : 8);
}

// Round 8
// 213.905 us; speedup vs baseline: 1.2189x; 1.2189x over previous
//
#include <hip/hip_runtime.h>
#include <math.h>

#define NIMG 32
#define NB3  771             // 257 rings * 3 sums
#define PI_F 3.14159265358979323846f

// ---------------------------------------------------------------------------
__device__ __forceinline__ float2 cadd(float2 a, float2 b){ return make_float2(a.x+b.x, a.y+b.y); }
__device__ __forceinline__ float2 csub(float2 a, float2 b){ return make_float2(a.x-b.x, a.y-b.y); }
__device__ __forceinline__ float2 cmul(float2 a, float2 b){ return make_float2(a.x*b.x - a.y*b.y, a.x*b.y + a.y*b.x); }
__device__ __forceinline__ float2 cmul_mi(float2 a){ return make_float2(a.y, -a.x); }   // * (-i)
__device__ __forceinline__ float2 tw(const float2* T, int m){ return T[m + (m >> 3)]; }
__device__ __forceinline__ int   sw(int pos){ return pos + (pos >> 3); }     // LDS pad swizzle

// 8-point DFT (DIF, natural-order outputs), e^{-2pi i/8} convention
__device__ __forceinline__ void dft8(float2* x) {
    const float c = 0.70710678118654752f;
    float2 u0 = cadd(x[0], x[4]), u1 = cadd(x[1], x[5]);
    float2 u2 = cadd(x[2], x[6]), u3 = cadd(x[3], x[7]);
    float2 v0 = csub(x[0], x[4]);
    float2 d1 = csub(x[1], x[5]);
    float2 v1 = make_float2(c*(d1.x + d1.y), c*(d1.y - d1.x));
    float2 d2 = csub(x[2], x[6]);
    float2 v2 = make_float2(d2.y, -d2.x);
    float2 d3 = csub(x[3], x[7]);
    float2 v3 = make_float2(-c*(d3.x - d3.y), -c*(d3.x + d3.y));
    float2 e0 = cadd(u0,u2), e1 = cadd(u1,u3);
    float2 f0 = csub(u0,u2), f1 = cmul_mi(csub(u1,u3));
    float2 g0 = cadd(v0,v2), g1 = cadd(v1,v3);
    float2 h0 = csub(v0,v2), h1 = cmul_mi(csub(v1,v3));
    x[0] = cadd(e0,e1); x[4] = csub(e0,e1);
    x[2] = cadd(f0,f1); x[6] = csub(f0,f1);
    x[1] = cadd(g0,g1); x[5] = csub(g0,g1);
    x[3] = cadd(h0,h1); x[7] = csub(h0,h1);
}

// ---------------------------------------------------------------------------
// Per-wave 512-pt radix-8 DIF FFT, barrier-free (wave-private 576-slot LDS
// scratch; one wave's LDS ops execute in order). Thread J enters with
// X[q] = x[J + 64q], exits with X[k] = F(64k + r), r = 8*(J&7) + (J>>3).
// ---------------------------------------------------------------------------
__device__ __forceinline__ void wave_fft512(float2* X, float2* Sw,
                                            const float2* T, int J) {
    dft8(X);
#pragma unroll
    for (int k = 1; k < 8; ++k) X[k] = cmul(X[k], tw(T, J * k));
    const int jj = J + (J >> 3);
#pragma unroll
    for (int k = 0; k < 8; ++k) Sw[jj + 72*k] = X[k];

    const int j2 = J & 7;
    const int bb = 72 * (J >> 3) + j2;
#pragma unroll
    for (int q = 0; q < 8; ++q) X[q] = Sw[bb + 9*q];
    dft8(X);
#pragma unroll
    for (int k = 1; k < 8; ++k) X[k] = cmul(X[k], tw(T, 8 * j2 * k));
#pragma unroll
    for (int k = 0; k < 8; ++k) Sw[bb + 9*k] = X[k];

#pragma unroll
    for (int q = 0; q < 8; ++q) X[q] = Sw[9*J + q];
    dft8(X);
}

// ---------------------------------------------------------------------------
// Row pass (unchanged — control variable). Writes transposed Zt[kx][y].
// ---------------------------------------------------------------------------
__global__ __launch_bounds__(256, 6) void fft_rows_T(const float* __restrict__ xr,
                                                     const float* __restrict__ yr,
                                                     float2* __restrict__ Zt) {
    __shared__ float2 S[4 * 576];
    __shared__ float2 T[576];
    const int t = threadIdx.x, w = t >> 6, J = t & 63;
    const int im = blockIdx.x >> 6, grp = blockIdx.x & 63;

#pragma unroll
    for (int i = 0; i < 2; ++i) {
        const int m = t + 256 * i;
        float s, c;
        __sincosf(-2.0f * PI_F * (float)m / 512.0f, &s, &c);
        T[m + (m >> 3)] = make_float2(c, s);
    }

    const size_t b0 = ((size_t)(im * 512 + grp * 8 + w)) << 9;
    const size_t b1 = b0 + (4u << 9);
    float2 X0[8], X1[8];
#pragma unroll
    for (int q = 0; q < 8; ++q) {
        X0[q] = make_float2(xr[b0 + J + 64*q], yr[b0 + J + 64*q]);
        X1[q] = make_float2(xr[b1 + J + 64*q], yr[b1 + J + 64*q]);
    }
    __syncthreads();                       // T ready

    float2* Sw = S + w * 576;
    wave_fft512(X0, Sw, T, J);
    wave_fft512(X1, Sw, T, J);

    const int r = ((J & 7) << 3) | (J >> 3);

#pragma unroll
    for (int k = 0; k < 8; ++k) Sw[64*k + r] = X0[k];
    __syncthreads();
    float2 eA[4], eB[4];
#pragma unroll
    for (int j = 0; j < 4; ++j) { eA[j] = S[j*576 + t]; eB[j] = S[j*576 + t + 256]; }
    __syncthreads();

#pragma unroll
    for (int k = 0; k < 8; ++k) Sw[64*k + r] = X1[k];
    __syncthreads();

    const size_t zb = ((size_t)im << 18) + (grp << 3);
    {
        float4* o = (float4*)(Zt + zb + ((size_t)t << 9));
        float2 f0 = S[0*576 + t], f1 = S[1*576 + t];
        float2 f2 = S[2*576 + t], f3 = S[3*576 + t];
        o[0] = make_float4(eA[0].x, eA[0].y, eA[1].x, eA[1].y);
        o[1] = make_float4(eA[2].x, eA[2].y, eA[3].x, eA[3].y);
        o[2] = make_float4(f0.x, f0.y, f1.x, f1.y);
        o[3] = make_float4(f2.x, f2.y, f3.x, f3.y);
    }
    {
        float4* o = (float4*)(Zt + zb + ((size_t)(t + 256) << 9));
        float2 f0 = S[0*576 + t + 256], f1 = S[1*576 + t + 256];
        float2 f2 = S[2*576 + t + 256], f3 = S[3*576 + t + 256];
        o[0] = make_float4(eB[0].x, eB[0].y, eB[1].x, eB[1].y);
        o[1] = make_float4(eB[2].x, eB[2].y, eB[3].x, eB[3].y);
        o[2] = make_float4(f0.x, f0.y, f1.x, f1.y);
        o[3] = make_float4(f2.x, f2.y, f3.x, f3.y);
    }
}

// ---------------------------------------------------------------------------
// Fused column FFT + rings, v2. Wave w of block g owns mirror pair p = 4g+w:
//   p = 0 : columns (0, 256), each self-mirror
//   p >= 1: columns (p, 512-p) — pixel (p,ky) and (512-p,512-ky) share a ring
//           AND share the two values {P0[ky], P1[512-ky]} -> lane-local, no shfl.
// Each wave: FFT col A in region A, park natural-order (swizzled) in A;
// same for col B in region B. Ring phase: lane J reads consecutive ky=8J..8J+7
// (ring index monotone per lane) and run-merges deposits -> ~2-way atomic
// collisions instead of up to 64-way. Only 2 block barriers total.
// ---------------------------------------------------------------------------
__global__ __launch_bounds__(256) void fft_cols_rings(const float2* __restrict__ Zt,
                                                      float* __restrict__ sums,
                                                      int big) {
    __shared__ float2 S[8 * 576];      // 2 regions per wave: 36,864 B
    __shared__ float2 T[576];          //  4,608 B
    __shared__ float  bins[258 * 3];   //  3,096 B
    const int t = threadIdx.x, w = t >> 6, J = t & 63;
    const int im = blockIdx.x >> 6, g = blockIdx.x & 63;
    const int p = 4 * g + w;

#pragma unroll
    for (int i = 0; i < 2; ++i) {
        const int m = t + 256 * i;
        float s, c;
        __sincosf(-2.0f * PI_F * (float)m / 512.0f, &s, &c);
        T[m + (m >> 3)] = make_float2(c, s);
    }
    for (int i = t; i < 258 * 3; i += 256) bins[i] = 0.0f;

    const int c0 = (p == 0) ? 0   : p;
    const int c1 = (p == 0) ? 256 : 512 - p;
    const float2* rp0 = Zt + ((size_t)im << 18) + ((size_t)c0 << 9);
    const float2* rp1 = Zt + ((size_t)im << 18) + ((size_t)c1 << 9);
    float2 X0[8], X1[8];
#pragma unroll
    for (int q = 0; q < 8; ++q) { X0[q] = rp0[J + 64*q]; X1[q] = rp1[J + 64*q]; }
    __syncthreads();                       // T ready, bins zeroed

    float2* A = S + (2*w) * 576;
    float2* B = A + 576;
    const int r  = ((J & 7) << 3) | (J >> 3);
    const int pk = r + (r >> 3);           // sw(64k + r) = 72k + pk

    wave_fft512(X0, A, T, J);              // scratch A (reads precede writes in-wave)
#pragma unroll
    for (int k = 0; k < 8; ++k) A[72*k + pk] = X0[k];    // park natural order
    wave_fft512(X1, B, T, J);
#pragma unroll
    for (int k = 0; k < 8; ++k) B[72*k + pk] = X1[k];

    // ---- ring phase: wave-private LDS reads, run-merged LDS-atomic deposits
    const float scale = 1.0f / (512.0f * 512.0f);
    auto pix = [&](float2 zk, float2 zm, float& av, float& c1v, float& c2v) {
        float f1r = 0.5f * (zk.x + zm.x) * scale;
        float f1i = 0.5f * (zk.y - zm.y) * scale;
        float f2r = 0.5f * (zk.y + zm.y) * scale;
        float f2i = 0.5f * (zm.x - zk.x) * scale;
        av  = f1r * f2r + f1i * f2i;
        c1v = f1r * f1r + f1i * f1i;
        c2v = f2r * f2r + f2i * f2i;
    };
    auto flush = [&](int ring, float a, float b, float c) {
        if (ring >= 0 && ring <= 256) {
            unsafeAtomicAdd(&bins[ring*3+0], a);
            unsafeAtomicAdd(&bins[ring*3+1], b);
            unsafeAtomicAdd(&bins[ring*3+2], c);
        }
    };

    if (p == 0) {
        int cur0 = -1, cur1 = -1;
        float a0 = 0, b0 = 0, c0v = 0, a1 = 0, b1 = 0, c1v = 0;
#pragma unroll
        for (int i = 0; i < 8; ++i) {
            const int ky  = 8*J + i;
            const int kyp = (512 - ky) & 511;
            float2 zk0 = A[sw(ky)], zm0 = A[sw(kyp)];
            float2 zk1 = B[sw(ky)], zm1 = B[sw(kyp)];
            const float fk = (ky < 256) ? (float)ky : (float)(ky - 512);
            float av, cv, dv;
            pix(zk0, zm0, av, cv, dv);                     // col 0, fy = 0
            int rr = (int)rintf(fabsf(fk)); if (rr > 256) rr = 257;
            if (rr != cur0) { flush(cur0, a0, b0, c0v); cur0 = rr; a0 = av; b0 = cv; c0v = dv; }
            else            { a0 += av; b0 += cv; c0v += dv; }
            pix(zk1, zm1, av, cv, dv);                     // col 256, fy = 256
            rr = (int)rintf(sqrtf(fk*fk + 65536.0f)); if (rr > 256) rr = 257;
            if (rr != cur1) { flush(cur1, a1, b1, c1v); cur1 = rr; a1 = av; b1 = cv; c1v = dv; }
            else            { a1 += av; b1 += cv; c1v += dv; }
        }
        flush(cur0, a0, b0, c0v);
        flush(cur1, a1, b1, c1v);
    } else {
        const float fy2 = (float)p * (float)p;
        int curR = -1;
        float sA = 0, sB = 0, sC = 0;
#pragma unroll
        for (int i = 0; i < 8; ++i) {
            const int ky  = 8*J + i;
            const int kyp = (512 - ky) & 511;
            float2 zk = A[sw(ky)];           // P0[ky]
            float2 zm = B[sw(kyp)];          // P1[512-ky]
            float a1v, b1v, d1v, a2v, b2v, d2v;
            pix(zk, zm, a1v, b1v, d1v);      // pixel (p, ky),       partner (512-p, 512-ky)
            pix(zm, zk, a2v, b2v, d2v);      // pixel (512-p,512-ky), partner (p, ky)
            const float fk = (ky < 256) ? (float)ky : (float)(ky - 512);
            int rr = (int)rintf(sqrtf(fk*fk + fy2)); if (rr > 256) rr = 257;
            const float aa = a1v + a2v, bb = b1v + b2v, cc = d1v + d2v;
            if (rr != curR) { flush(curR, sA, sB, sC); curR = rr; sA = aa; sB = bb; sC = cc; }
            else            { sA += aa; sB += bb; sC += cc; }
        }
        flush(curR, sA, sB, sC);
    }
    __syncthreads();

    if (big) {
        float* dst = sums + (size_t)blockIdx.x * NB3;          // private slice
        for (int i = t; i < NB3; i += 256) dst[i] = bins[i];
    } else {
        float* dst = sums + (size_t)(im * 8 + (g & 7)) * NB3;  // shared slice
        for (int i = t; i < NB3; i += 256) unsafeAtomicAdd(&dst[i], bins[i]);
    }
}

// ---------------------------------------------------------------------------
// Finalize: block = image; sum spi slices per ring; mean of (1-frc)^2.
// C_i ring sums are exactly 0 by k -> -k antisymmetry; dropped.
// ---------------------------------------------------------------------------
__global__ __launch_bounds__(256) void finalize(const float* __restrict__ sums,
                                                float* __restrict__ out, int spi) {
    const int b = blockIdx.x, t = threadIdx.x;
    float acc = 0.0f;
    for (int r = t; r < 257; r += 256) {
        float cr = 0.f, c1 = 0.f, c2 = 0.f;
        for (int s = 0; s < spi; ++s) {
            const float* pp = sums + (size_t)(b * spi + s) * NB3 + r * 3;
            cr += pp[0]; c1 += pp[1]; c2 += pp[2];
        }
        float frc = fabsf(cr) / (sqrtf(c1 * c2) + 1e-8f);
        float d = 1.0f - frc;
        acc += d * d;
    }
#pragma unroll
    for (int off = 32; off > 0; off >>= 1) acc += __shfl_down(acc, off);
    __shared__ float red[4];
    if ((t & 63) == 0) red[t >> 6] = acc;
    __syncthreads();
    if (t == 0)
        unsafeAtomicAdd(out, (red[0] + red[1] + red[2] + red[3]) *
                             (1.0f / (257.0f * (float)NIMG)));
}

// ---------------------------------------------------------------------------
extern "C" void kernel_launch(void* const* d_in, const int* in_sizes, int n_in,
                              void* d_out, int out_size, void* d_ws, size_t ws_size,
                              hipStream_t stream) {
    const float* xr = (const float*)d_in[0];   // output: 32x1x512x512 f32
    const float* yr = (const float*)d_in[1];   // target: 32x1x512x512 f32

    float2* Zt = (float2*)d_ws;                                    // 64 MiB
    const size_t ztBytes = ((size_t)NIMG << 18) * sizeof(float2);
    float* sums = (float*)((char*)d_ws + ztBytes);
    const int big = (ws_size >= ztBytes + (size_t)2048 * NB3 * sizeof(float)) ? 1 : 0;

    if (!big)
        hipMemsetAsync(sums, 0, (size_t)NIMG * 8 * NB3 * sizeof(float), stream);
    hipMemsetAsync(d_out, 0, sizeof(float), stream);

    fft_rows_T    <<<dim3(NIMG * 64), dim3(256), 0, stream>>>(xr, yr, Zt);
    fft_cols_rings<<<dim3(NIMG * 64), dim3(256), 0, stream>>>(Zt, sums, big);
    finalize      <<<dim3(NIMG), dim3(256), 0, stream>>>(sums, (float*)d_out, big ? 64 : 8);
}